// Round 2
// 450.537 us; speedup vs baseline: 1.0538x; 1.0538x over previous
//
#include <hip/hip_runtime.h>
#include <hip/hip_bf16.h>

// ---------------------------------------------------------------------------
// BinarizedLayer: out[m,n] = sum_k x[m,k] * wbin[n,k] + bias[n]
//   wbin = (w < (upper-lower)) ? lower : upper,  upper=max(c1,c2), lower=min
// M=16384 (B*S), K=1024 (DIN), N=4096 (DOUT). fp32 in/out.
// v2b: 256x256-tile 8-wave GEMM with counted-vmcnt 4-slot LDS ring (BK=32),
//      XOR bank swizzle (pre-swizzled global source + swizzled ds_read),
//      setprio around MFMA cluster, XCD-aware block swizzle, NT C stores.
//      Prep (x->bf16, w binarize->bf16) fused into one launch.
// ---------------------------------------------------------------------------

typedef __bf16 bf16x8 __attribute__((ext_vector_type(8)));
typedef float  f32x4  __attribute__((ext_vector_type(4)));

__device__ inline unsigned short f2bf(float f) {
    unsigned int u = __float_as_uint(f);
    u += 0x7FFFu + ((u >> 16) & 1u);   // round-to-nearest-even
    return (unsigned short)(u >> 16);
}

// ---- prep: x fp32->bf16 AND w binarize->bf16, one launch ------------------
__global__ void prep_kernel(const float4* __restrict__ x,
                            ushort4* __restrict__ xb, int nx4,
                            const float4* __restrict__ w,
                            ushort4* __restrict__ wb, int nw4,
                            const float* __restrict__ c1,
                            const float* __restrict__ c2) {
    const float a = c1[0], b = c2[0];
    const float upper  = fmaxf(a, b);
    const float lower  = fminf(a, b);
    const float middle = upper - lower;          // threshold, as reference
    const unsigned short lo16 = f2bf(lower);
    const unsigned short up16 = f2bf(upper);
    const int total  = nx4 + nw4;
    const int stride = gridDim.x * blockDim.x;
    for (int i = blockIdx.x * blockDim.x + threadIdx.x; i < total; i += stride) {
        if (i < nx4) {
            float4 v = x[i];
            ushort4 o;
            o.x = f2bf(v.x); o.y = f2bf(v.y);
            o.z = f2bf(v.z); o.w = f2bf(v.w);
            xb[i] = o;
        } else {
            const int j = i - nx4;
            float4 v = w[j];
            ushort4 o;
            o.x = (v.x < middle) ? lo16 : up16;
            o.y = (v.y < middle) ? lo16 : up16;
            o.z = (v.z < middle) ? lo16 : up16;
            o.w = (v.w < middle) ? lo16 : up16;
            wb[j] = o;
        }
    }
}

// ---- async 16B global -> LDS ----------------------------------------------
__device__ inline void async16(void* lds, const void* g) {
    __builtin_amdgcn_global_load_lds(
        (const __attribute__((address_space(1))) void*)g,
        (__attribute__((address_space(3))) void*)lds,
        16, 0, 0);
}

// barrier with compiler memory fences on both sides (raw s_barrier builtin
// alone does not stop LLVM from moving LDS loads across it)
#define BAR() do {                                   \
    asm volatile("" ::: "memory");                   \
    __builtin_amdgcn_s_barrier();                    \
    asm volatile("" ::: "memory");                   \
} while (0)

// ---- GEMM: C[m,n] = sum_k A[m,k]*B[n,k] + bias[n] (A,B bf16 bits, C fp32) -
// 256x256 tile, BK=32, 512 threads = 8 waves (2M x 4N), each wave 128x64 via
// 8x4 grid of 16x16x32 MFMA. LDS: 4-slot ring x (A 16KiB | B 16KiB) = 128 KiB.
// Schedule: while computing K-tile t (2 phases), stage K-tile t+2 into slot
// (t+2)&3; at each tile boundary wait vmcnt(4) (t+1's 4 issues landed, t+2's
// 4 still in flight) — never vmcnt(0) in the main loop.
// Swizzle: 16B unit u at LDS row r holds logical unit u ^ ((r>>1)&3)
// (involution; applied to per-lane global source at stage time and to the
// ds_read address at read time; LDS dest of global_load_lds stays linear).
__global__ __launch_bounds__(512, 2) void gemm_bin(
        const ushort* __restrict__ A,   // [M][K] bf16 bits
        const ushort* __restrict__ B,   // [N][K] bf16 bits
        const float*  __restrict__ bias,
        float* __restrict__ C,
        int M, int N, int K) {
    __shared__ ushort lds[4 * 16384];   // 4 slots x 32 KiB

    const int tid  = threadIdx.x;
    const int wave = tid >> 6;
    const int lane = tid & 63;

    // XCD-aware swizzle: each XCD gets a contiguous chunk of the grid
    const int nwg = gridDim.x;
    int wg = blockIdx.x;
    if ((nwg & 7) == 0) {
        const int cpx = nwg >> 3;
        wg = (wg & 7) * cpx + (wg >> 3);
    }
    const int nbn = N >> 8;             // N/256
    const int bm = wg / nbn, bn = wg - bm * nbn;
    const int row0 = bm << 8, col0 = bn << 8;

    const int wm = (wave >> 2) * 128;   // 0 or 128
    const int wn = (wave & 3) * 64;     // 0,64,128,192

    // ---- staging addresses (issue granularity: 8 KiB = 128 rows x 32 cols)
    // phys byte within a 16KiB part: p = issue*8192 + wave*1024 + lane*16
    //   row = p>>6, unit = (p>>4)&3; logical unit = unit ^ ((row>>1)&3)
    const int srow  = wave * 16 + (lane >> 2);              // rows for issue 0
    const int sulog = (lane & 3) ^ ((srow >> 1) & 3);       // same for issue 1
    const ushort* aS0 = A + (size_t)(row0 + srow) * K + sulog * 8;
    const ushort* aS1 = aS0 + (size_t)128 * K;
    const ushort* bS0 = B + (size_t)(col0 + srow) * K + sulog * 8;
    const ushort* bS1 = bS0 + (size_t)128 * K;
    // wave-uniform LDS dests (ushort units), add slot*16384 per tile
    ushort* const ldsA0 = &lds[        wave * 512];
    ushort* const ldsA1 = &lds[ 4096 + wave * 512];
    ushort* const ldsB0 = &lds[ 8192 + wave * 512];
    ushort* const ldsB1 = &lds[12288 + wave * 512];

    // ---- fragment read offsets (swizzled) ----
    // logical (row, k-unit cu) lives at phys ushort  row*32 + (cu^((row>>1)&3))*8
    // row = w? + i*16 + fr with (w? + i*16) ≡ 0 mod 4 after >>1  =>  sw=(fr>>1)&3
    const int fr = lane & 15;
    const int cu = lane >> 4;           // k = cu*8 .. cu*8+7
    const int sw = (fr >> 1) & 3;
    const int aOff =        (wm + fr) * 32 + ((cu ^ sw) * 8);
    const int bOff = 8192 + (wn + fr) * 32 + ((cu ^ sw) * 8);

    f32x4 acc[8][4];
#pragma unroll
    for (int i = 0; i < 8; ++i)
#pragma unroll
        for (int j = 0; j < 4; ++j)
            acc[i][j] = (f32x4){0.f, 0.f, 0.f, 0.f};

    const int NT = K >> 5;              // K-tiles of 32

    // ---- prologue: stage tiles 0 -> slot0, 1 -> slot1 (8 issues/wave) ----
    async16(ldsA0,         aS0);
    async16(ldsA1,         aS1);
    async16(ldsB0,         bS0);
    async16(ldsB1,         bS1);
    async16(ldsA0 + 16384, aS0 + 32);
    async16(ldsA1 + 16384, aS1 + 32);
    async16(ldsB0 + 16384, bS0 + 32);
    async16(ldsB1 + 16384, bS1 + 32);
    asm volatile("s_waitcnt vmcnt(4)" ::: "memory");   // tile 0 landed
    BAR();

    for (int t = 0; t < NT; ++t) {
        const int sb = (t & 3) * 16384;            // compute slot
        const int ss = ((t + 2) & 3) * 16384;      // stage slot
        const size_t kofs = (size_t)(t + 2) * 32;
        const bool doStage = (t + 2) < NT;

        bf16x8 af[4], bf[4];

        // ---------------- phase 0: i = 0..3, all j ----------------
#pragma unroll
        for (int i = 0; i < 4; ++i)
            af[i] = *(const bf16x8*)&lds[sb + aOff + i * 512];
#pragma unroll
        for (int j = 0; j < 4; ++j)
            bf[j] = *(const bf16x8*)&lds[sb + bOff + j * 512];
        if (doStage) {
            async16(ldsA0 + ss, aS0 + kofs);
            async16(ldsB0 + ss, bS0 + kofs);
        }
        BAR();
        asm volatile("s_waitcnt lgkmcnt(0)" ::: "memory");
        __builtin_amdgcn_sched_barrier(0);
        __builtin_amdgcn_s_setprio(1);
#pragma unroll
        for (int i = 0; i < 4; ++i)
#pragma unroll
            for (int j = 0; j < 4; ++j)
                acc[i][j] = __builtin_amdgcn_mfma_f32_16x16x32_bf16(
                    af[i], bf[j], acc[i][j], 0, 0, 0);
        __builtin_amdgcn_s_setprio(0);
        BAR();

        // ---------------- phase 1: i = 4..7, reuse bf ----------------
#pragma unroll
        for (int i = 0; i < 4; ++i)
            af[i] = *(const bf16x8*)&lds[sb + aOff + (i + 4) * 512];
        if (doStage) {
            async16(ldsA1 + ss, aS1 + kofs);
            async16(ldsB1 + ss, bS1 + kofs);
        }
        // counted wait for NEXT tile's data (4 = this tile's stage issues
        // still in flight); only drains to 0 for the final tile
        if (t < NT - 2)
            asm volatile("s_waitcnt vmcnt(4)" ::: "memory");
        else if (t == NT - 2)
            asm volatile("s_waitcnt vmcnt(0)" ::: "memory");
        BAR();
        asm volatile("s_waitcnt lgkmcnt(0)" ::: "memory");
        __builtin_amdgcn_sched_barrier(0);
        __builtin_amdgcn_s_setprio(1);
#pragma unroll
        for (int i = 0; i < 4; ++i)
#pragma unroll
            for (int j = 0; j < 4; ++j)
                acc[i + 4][j] = __builtin_amdgcn_mfma_f32_16x16x32_bf16(
                    af[i], bf[j], acc[i + 4][j], 0, 0, 0);
        __builtin_amdgcn_s_setprio(0);
        BAR();
    }

    // ---- epilogue: C/D layout col=lane&15, row=(lane>>4)*4+reg ----
    const int er = (lane >> 4) * 4;
    const int ec = lane & 15;
#pragma unroll
    for (int j = 0; j < 4; ++j) {
        const int col = col0 + wn + j * 16 + ec;
        const float bz = bias[col];
#pragma unroll
        for (int i = 0; i < 8; ++i) {
            const size_t rbase = (size_t)(row0 + wm + i * 16 + er) * N + col;
#pragma unroll
            for (int r = 0; r < 4; ++r)
                __builtin_nontemporal_store(acc[i][j][r] + bz,
                                            &C[rbase + (size_t)r * N]);
        }
    }
}

extern "C" void kernel_launch(void* const* d_in, const int* in_sizes, int n_in,
                              void* d_out, int out_size, void* d_ws, size_t ws_size,
                              hipStream_t stream) {
    const float* x    = (const float*)d_in[0];   // [M][K]
    const float* w    = (const float*)d_in[1];   // [N][K]
    const float* c1   = (const float*)d_in[2];
    const float* c2   = (const float*)d_in[3];
    const float* bias = (const float*)d_in[4];   // [N]
    float* out = (float*)d_out;

    const int DOUT = in_sizes[4];                // 4096
    const int DIN  = in_sizes[1] / DOUT;         // 1024
    const int M    = in_sizes[0] / DIN;          // 16384
    const int N    = DOUT;
    const int K    = DIN;

    // workspace: x_bf16 (M*K ushort) then w_bf16 (N*K ushort) = 40 MB
    ushort* xb = (ushort*)d_ws;
    ushort* wb = xb + (size_t)M * K;

    const int nx4 = (M * K) / 4;
    const int nw4 = (N * K) / 4;
    prep_kernel<<<2048, 256, 0, stream>>>((const float4*)x, (ushort4*)xb, nx4,
                                          (const float4*)w, (ushort4*)wb, nw4,
                                          c1, c2);

    dim3 grid((M / 256) * (N / 256));            // 1024 blocks
    gemm_bin<<<grid, 512, 0, stream>>>(xb, wb, bias, out, M, N, K);
}

// Round 3
// 442.713 us; speedup vs baseline: 1.0724x; 1.0177x over previous
//
#include <hip/hip_runtime.h>
#include <hip/hip_bf16.h>

// ---------------------------------------------------------------------------
// BinarizedLayer: out[m,n] = sum_k x[m,k] * wbin[n,k] + bias[n]
//   wbin = (w < (upper-lower)) ? lower : upper,  upper=max(c1,c2), lower=min
// M=16384 (B*S), K=1024 (DIN), N=4096 (DOUT). fp32 in/out.
// v3: schedule identical to v2 (256x256 tile, 8 waves, BK=32, 4-slot
//     counted-vmcnt LDS ring, XOR swizzle, setprio, XCD swizzle, NT stores)
//     but K-loop UNROLLED x4 so every LDS address is base + compile-time
//     immediate (slot index t&3 static per copy) — removes the per-phase
//     runtime address VALU that was inflating the barrier-locked sections.
// ---------------------------------------------------------------------------

typedef __bf16 bf16x8 __attribute__((ext_vector_type(8)));
typedef float  f32x4  __attribute__((ext_vector_type(4)));

__device__ inline unsigned short f2bf(float f) {
    unsigned int u = __float_as_uint(f);
    u += 0x7FFFu + ((u >> 16) & 1u);   // round-to-nearest-even
    return (unsigned short)(u >> 16);
}

// ---- prep: x fp32->bf16 AND w binarize->bf16, one launch ------------------
__global__ void prep_kernel(const float4* __restrict__ x,
                            ushort4* __restrict__ xb, int nx4,
                            const float4* __restrict__ w,
                            ushort4* __restrict__ wb, int nw4,
                            const float* __restrict__ c1,
                            const float* __restrict__ c2) {
    const float a = c1[0], b = c2[0];
    const float upper  = fmaxf(a, b);
    const float lower  = fminf(a, b);
    const float middle = upper - lower;          // threshold, as reference
    const unsigned short lo16 = f2bf(lower);
    const unsigned short up16 = f2bf(upper);
    const int total  = nx4 + nw4;
    const int stride = gridDim.x * blockDim.x;
    for (int i = blockIdx.x * blockDim.x + threadIdx.x; i < total; i += stride) {
        if (i < nx4) {
            float4 v = x[i];
            ushort4 o;
            o.x = f2bf(v.x); o.y = f2bf(v.y);
            o.z = f2bf(v.z); o.w = f2bf(v.w);
            xb[i] = o;
        } else {
            const int j = i - nx4;
            float4 v = w[j];
            ushort4 o;
            o.x = (v.x < middle) ? lo16 : up16;
            o.y = (v.y < middle) ? lo16 : up16;
            o.z = (v.z < middle) ? lo16 : up16;
            o.w = (v.w < middle) ? lo16 : up16;
            wb[j] = o;
        }
    }
}

// ---- async 16B global -> LDS ----------------------------------------------
__device__ inline void async16(void* lds, const void* g) {
    __builtin_amdgcn_global_load_lds(
        (const __attribute__((address_space(1))) void*)g,
        (__attribute__((address_space(3))) void*)lds,
        16, 0, 0);
}

#define BAR() do {                                   \
    asm volatile("" ::: "memory");                   \
    __builtin_amdgcn_s_barrier();                    \
    asm volatile("" ::: "memory");                   \
} while (0)

// ---- GEMM: C[m,n] = sum_k A[m,k]*B[n,k] + bias[n] (A,B bf16 bits, C fp32) -
__global__ __launch_bounds__(512, 2) void gemm_bin(
        const ushort* __restrict__ A,   // [M][K] bf16 bits
        const ushort* __restrict__ B,   // [N][K] bf16 bits
        const float*  __restrict__ bias,
        float* __restrict__ C,
        int M, int N, int K) {
    __shared__ ushort lds[4 * 16384];   // 4 slots x 32 KiB

    const int tid  = threadIdx.x;
    const int wave = tid >> 6;
    const int lane = tid & 63;

    // XCD-aware swizzle: each XCD gets a contiguous chunk of the grid
    const int nwg = gridDim.x;
    int wg = blockIdx.x;
    if ((nwg & 7) == 0) {
        const int cpx = nwg >> 3;
        wg = (wg & 7) * cpx + (wg >> 3);
    }
    const int nbn = N >> 8;             // N/256
    const int bm = wg / nbn, bn = wg - bm * nbn;
    const int row0 = bm << 8, col0 = bn << 8;

    const int wm = (wave >> 2) * 128;   // 0 or 128
    const int wn = (wave & 3) * 64;     // 0,64,128,192

    // ---- staging addresses (issue granularity: 8 KiB = 128 rows x 32 cols)
    // phys byte within a 16KiB part: p = issue*8192 + wave*1024 + lane*16
    //   row = p>>6, unit = (p>>4)&3; logical unit = unit ^ ((row>>1)&3)
    const int srow  = wave * 16 + (lane >> 2);
    const int sulog = (lane & 3) ^ ((srow >> 1) & 3);
    const ushort* pa0 = A + (size_t)(row0 + srow) * K + sulog * 8;
    const ushort* pa1 = pa0 + (size_t)128 * K;
    const ushort* pb0 = B + (size_t)(col0 + srow) * K + sulog * 8;
    const ushort* pb1 = pb0 + (size_t)128 * K;
    // wave-uniform LDS dests (ushort units); + slot*16384 static per copy
    ushort* const sA0 = &lds[        wave * 512];
    ushort* const sA1 = &lds[ 4096 + wave * 512];
    ushort* const sB0 = &lds[ 8192 + wave * 512];
    ushort* const sB1 = &lds[12288 + wave * 512];

    // ---- fragment read bases (swizzled); slots 0-1 off vX[0], 2-3 off vX[1]
    // logical (row, k-unit cu) lives at phys ushort  row*32 + (cu^((row>>1)&3))*8
    const int fr = lane & 15;
    const int cu = lane >> 4;
    const int sw = (fr >> 1) & 3;
    const int aByte = ((wm + fr) * 32 + (cu ^ sw) * 8) * 2;
    const int bByte = 16384 + ((wn + fr) * 32 + (cu ^ sw) * 8) * 2;
    const char* const ldsc = (const char*)lds;
    const char* const vA[2] = { ldsc + aByte, ldsc + 65536 + aByte };
    const char* const vB[2] = { ldsc + bByte, ldsc + 65536 + bByte };

    f32x4 acc[8][4];
#pragma unroll
    for (int i = 0; i < 8; ++i)
#pragma unroll
        for (int j = 0; j < 4; ++j)
            acc[i][j] = (f32x4){0.f, 0.f, 0.f, 0.f};

    const int NT  = K >> 5;             // K-tiles of 32 (=32 for K=1024)
    const int NTM = NT >> 2;            // macro-iters (K % 128 == 0)

    // ---- prologue: stage tiles 0 -> slot0, 1 -> slot1 (8 issues/wave) ----
    async16(sA0,         pa0);
    async16(sA1,         pa1);
    async16(sB0,         pb0);
    async16(sB1,         pb1);
    async16(sA0 + 16384, pa0 + 32);
    async16(sA1 + 16384, pa1 + 32);
    async16(sB0 + 16384, pb0 + 32);
    async16(sB1 + 16384, pb1 + 32);
    asm volatile("s_waitcnt vmcnt(4)" ::: "memory");   // tile 0 landed
    BAR();

// One K-tile, compile-time copy index c in [0,4): slot = c, stage slot =
// (c+2)&3, stage k-imm = (c+2)*32 relative to pointers advanced per macro-iter.
#define TILE(c)                                                               \
    {                                                                         \
        const int t_ = tb + (c);                                              \
        constexpr int SB_ = ((c) & 1) * 32768;          /* read slot, bytes */\
        constexpr int SS_ = (((c) + 2) & 3) * 16384;    /* stage slot, ush  */\
        constexpr int KO_ = ((c) + 2) * 32;             /* stage k, ushorts */\
        const char* const vA_ = vA[(c) >> 1];                                 \
        const char* const vB_ = vB[(c) >> 1];                                 \
        const bool doStage_ = (t_ + 2) < NT;                                  \
        bf16x8 af[4], bf[4];                                                  \
        _Pragma("unroll")                                                     \
        for (int i = 0; i < 4; ++i)                                           \
            af[i] = *(const bf16x8*)(vA_ + SB_ + i * 1024);                   \
        _Pragma("unroll")                                                     \
        for (int j = 0; j < 4; ++j)                                           \
            bf[j] = *(const bf16x8*)(vB_ + SB_ + j * 1024);                   \
        if (doStage_) {                                                       \
            async16(sA0 + SS_, pa0 + KO_);                                    \
            async16(sB0 + SS_, pb0 + KO_);                                    \
        }                                                                     \
        BAR();                                                                \
        asm volatile("s_waitcnt lgkmcnt(0)" ::: "memory");                    \
        __builtin_amdgcn_sched_barrier(0);                                    \
        __builtin_amdgcn_s_setprio(1);                                        \
        _Pragma("unroll")                                                     \
        for (int i = 0; i < 4; ++i)                                           \
            _Pragma("unroll")                                                 \
            for (int j = 0; j < 4; ++j)                                       \
                acc[i][j] = __builtin_amdgcn_mfma_f32_16x16x32_bf16(          \
                    af[i], bf[j], acc[i][j], 0, 0, 0);                        \
        __builtin_amdgcn_s_setprio(0);                                        \
        BAR();                                                                \
        _Pragma("unroll")                                                     \
        for (int i = 0; i < 4; ++i)                                           \
            af[i] = *(const bf16x8*)(vA_ + SB_ + (4 + i) * 1024);             \
        if (doStage_) {                                                       \
            async16(sA1 + SS_, pa1 + KO_);                                    \
            async16(sB1 + SS_, pb1 + KO_);                                    \
        }                                                                     \
        if (t_ < NT - 2)                                                      \
            asm volatile("s_waitcnt vmcnt(4)" ::: "memory");                  \
        else if (t_ == NT - 2)                                                \
            asm volatile("s_waitcnt vmcnt(0)" ::: "memory");                  \
        BAR();                                                                \
        asm volatile("s_waitcnt lgkmcnt(0)" ::: "memory");                    \
        __builtin_amdgcn_sched_barrier(0);                                    \
        __builtin_amdgcn_s_setprio(1);                                        \
        _Pragma("unroll")                                                     \
        for (int i = 0; i < 4; ++i)                                           \
            _Pragma("unroll")                                                 \
            for (int j = 0; j < 4; ++j)                                       \
                acc[4 + i][j] = __builtin_amdgcn_mfma_f32_16x16x32_bf16(      \
                    af[i], bf[j], acc[4 + i][j], 0, 0, 0);                    \
        __builtin_amdgcn_s_setprio(0);                                        \
        BAR();                                                                \
    }

    for (int mt = 0; mt < NTM; ++mt) {
        const int tb = mt << 2;
        TILE(0)
        TILE(1)
        TILE(2)
        TILE(3)
        pa0 += 128; pa1 += 128; pb0 += 128; pb1 += 128;
    }
#undef TILE

    // ---- epilogue: C/D layout col=lane&15, row=(lane>>4)*4+reg ----
    const int er = (lane >> 4) * 4;
    const int ec = lane & 15;
#pragma unroll
    for (int j = 0; j < 4; ++j) {
        const int col = col0 + wn + j * 16 + ec;
        const float bz = bias[col];
#pragma unroll
        for (int i = 0; i < 8; ++i) {
            const size_t rbase = (size_t)(row0 + wm + i * 16 + er) * N + col;
#pragma unroll
            for (int r = 0; r < 4; ++r)
                __builtin_nontemporal_store(acc[i][j][r] + bz,
                                            &C[rbase + (size_t)r * N]);
        }
    }
}

extern "C" void kernel_launch(void* const* d_in, const int* in_sizes, int n_in,
                              void* d_out, int out_size, void* d_ws, size_t ws_size,
                              hipStream_t stream) {
    const float* x    = (const float*)d_in[0];   // [M][K]
    const float* w    = (const float*)d_in[1];   // [N][K]
    const float* c1   = (const float*)d_in[2];
    const float* c2   = (const float*)d_in[3];
    const float* bias = (const float*)d_in[4];   // [N]
    float* out = (float*)d_out;

    const int DOUT = in_sizes[4];                // 4096
    const int DIN  = in_sizes[1] / DOUT;         // 1024
    const int M    = in_sizes[0] / DIN;          // 16384
    const int N    = DOUT;
    const int K    = DIN;

    // workspace: x_bf16 (M*K ushort) then w_bf16 (N*K ushort) = 40 MB
    ushort* xb = (ushort*)d_ws;
    ushort* wb = xb + (size_t)M * K;

    const int nx4 = (M * K) / 4;
    const int nw4 = (N * K) / 4;
    prep_kernel<<<2048, 256, 0, stream>>>((const float4*)x, (ushort4*)xb, nx4,
                                          (const float4*)w, (ushort4*)wb, nw4,
                                          c1, c2);

    dim3 grid((M / 256) * (N / 256));            // 1024 blocks
    gemm_bin<<<grid, 512, 0, stream>>>(xb, wb, bias, out, M, N, K);
}

// Round 5
// 442.484 us; speedup vs baseline: 1.0729x; 1.0005x over previous
//
#include <hip/hip_runtime.h>
#include <hip/hip_bf16.h>

// ---------------------------------------------------------------------------
// BinarizedLayer: out[m,n] = sum_k x[m,k] * wbin[n,k] + bias[n]
//   wbin = (w < (upper-lower)) ? lower : upper,  upper=max(c1,c2), lower=min
// M=16384 (B*S), K=1024 (DIN), N=4096 (DOUT). fp32 in/out.
// v4b: resubmit of v4 (round-4 run died to container infra, not the kernel).
//     256x256 / 8-wave / BK=32 / 4-slot counted-vmcnt ring / XOR swizzle,
//     ONE barrier per K-tile: BAR; stage(t+2)x4; 12 ds_reads (bf first);
//     setprio(1); 32 MFMA; setprio(0); counted vmcnt(4). Ring depth 4 makes
//     the read slot never the written slot, so the tile-top barrier is the
//     only required sync per tile.
// ---------------------------------------------------------------------------

typedef __bf16 bf16x8 __attribute__((ext_vector_type(8)));
typedef float  f32x4  __attribute__((ext_vector_type(4)));

__device__ inline unsigned short f2bf(float f) {
    unsigned int u = __float_as_uint(f);
    u += 0x7FFFu + ((u >> 16) & 1u);   // round-to-nearest-even
    return (unsigned short)(u >> 16);
}

// ---- prep: x fp32->bf16 AND w binarize->bf16, one launch ------------------
__global__ void prep_kernel(const float4* __restrict__ x,
                            ushort4* __restrict__ xb, int nx4,
                            const float4* __restrict__ w,
                            ushort4* __restrict__ wb, int nw4,
                            const float* __restrict__ c1,
                            const float* __restrict__ c2) {
    const float a = c1[0], b = c2[0];
    const float upper  = fmaxf(a, b);
    const float lower  = fminf(a, b);
    const float middle = upper - lower;          // threshold, as reference
    const unsigned short lo16 = f2bf(lower);
    const unsigned short up16 = f2bf(upper);
    const int total  = nx4 + nw4;
    const int stride = gridDim.x * blockDim.x;
    for (int i = blockIdx.x * blockDim.x + threadIdx.x; i < total; i += stride) {
        if (i < nx4) {
            float4 v = x[i];
            ushort4 o;
            o.x = f2bf(v.x); o.y = f2bf(v.y);
            o.z = f2bf(v.z); o.w = f2bf(v.w);
            xb[i] = o;
        } else {
            const int j = i - nx4;
            float4 v = w[j];
            ushort4 o;
            o.x = (v.x < middle) ? lo16 : up16;
            o.y = (v.y < middle) ? lo16 : up16;
            o.z = (v.z < middle) ? lo16 : up16;
            o.w = (v.w < middle) ? lo16 : up16;
            wb[j] = o;
        }
    }
}

// ---- async 16B global -> LDS ----------------------------------------------
__device__ inline void async16(void* lds, const void* g) {
    __builtin_amdgcn_global_load_lds(
        (const __attribute__((address_space(1))) void*)g,
        (__attribute__((address_space(3))) void*)lds,
        16, 0, 0);
}

#define BAR() do {                                   \
    asm volatile("" ::: "memory");                   \
    __builtin_amdgcn_s_barrier();                    \
    asm volatile("" ::: "memory");                   \
} while (0)

// ---- GEMM: C[m,n] = sum_k A[m,k]*B[n,k] + bias[n] (A,B bf16 bits, C fp32) -
__global__ __launch_bounds__(512, 2) void gemm_bin(
        const ushort* __restrict__ A,   // [M][K] bf16 bits
        const ushort* __restrict__ B,   // [N][K] bf16 bits
        const float*  __restrict__ bias,
        float* __restrict__ C,
        int M, int N, int K) {
    __shared__ ushort lds[4 * 16384];   // 4 slots x 32 KiB

    const int tid  = threadIdx.x;
    const int wave = tid >> 6;
    const int lane = tid & 63;

    // XCD-aware swizzle: each XCD gets a contiguous chunk of the grid
    const int nwg = gridDim.x;
    int wg = blockIdx.x;
    if ((nwg & 7) == 0) {
        const int cpx = nwg >> 3;
        wg = (wg & 7) * cpx + (wg >> 3);
    }
    const int nbn = N >> 8;             // N/256
    const int bm = wg / nbn, bn = wg - bm * nbn;
    const int row0 = bm << 8, col0 = bn << 8;

    const int wm = (wave >> 2) * 128;   // 0 or 128
    const int wn = (wave & 3) * 64;     // 0,64,128,192

    // ---- staging addresses (issue granularity: 8 KiB = 128 rows x 32 cols)
    // phys byte within a 16KiB part: p = issue*8192 + wave*1024 + lane*16
    //   row = p>>6, unit = (p>>4)&3; logical unit = unit ^ ((row>>1)&3)
    const int srow  = wave * 16 + (lane >> 2);
    const int sulog = (lane & 3) ^ ((srow >> 1) & 3);
    const ushort* pa0 = A + (size_t)(row0 + srow) * K + sulog * 8;
    const ushort* pa1 = pa0 + (size_t)128 * K;
    const ushort* pb0 = B + (size_t)(col0 + srow) * K + sulog * 8;
    const ushort* pb1 = pb0 + (size_t)128 * K;
    // wave-uniform LDS dests (ushort units); + slot*16384 static per copy
    ushort* const sA0 = &lds[        wave * 512];
    ushort* const sA1 = &lds[ 4096 + wave * 512];
    ushort* const sB0 = &lds[ 8192 + wave * 512];
    ushort* const sB1 = &lds[12288 + wave * 512];

    // ---- fragment read bases (swizzled); slots 0-1 off vX[0], 2-3 off vX[1]
    // logical (row, k-unit cu) lives at phys ushort  row*32 + (cu^((row>>1)&3))*8
    const int fr = lane & 15;
    const int cu = lane >> 4;
    const int sw = (fr >> 1) & 3;
    const int aByte = ((wm + fr) * 32 + (cu ^ sw) * 8) * 2;
    const int bByte = 16384 + ((wn + fr) * 32 + (cu ^ sw) * 8) * 2;
    const char* const ldsc = (const char*)lds;
    const char* const vA[2] = { ldsc + aByte, ldsc + 65536 + aByte };
    const char* const vB[2] = { ldsc + bByte, ldsc + 65536 + bByte };

    f32x4 acc[8][4];
#pragma unroll
    for (int i = 0; i < 8; ++i)
#pragma unroll
        for (int j = 0; j < 4; ++j)
            acc[i][j] = (f32x4){0.f, 0.f, 0.f, 0.f};

    const int NT  = K >> 5;             // K-tiles of 32 (=32 for K=1024)
    const int NTM = NT >> 2;            // macro-iters (K % 128 == 0)

    // ---- prologue: stage tiles 0 -> slot0, 1 -> slot1 (8 issues/wave) ----
    async16(sA0,         pa0);
    async16(sA1,         pa1);
    async16(sB0,         pb0);
    async16(sB1,         pb1);
    async16(sA0 + 16384, pa0 + 32);
    async16(sA1 + 16384, pa1 + 32);
    async16(sB0 + 16384, pb0 + 32);
    async16(sB1 + 16384, pb1 + 32);
    asm volatile("s_waitcnt vmcnt(4)" ::: "memory");   // tile 0 landed

// One K-tile, compile-time copy index c in [0,4): read slot = c, stage slot =
// (c+2)&3, stage k-imm = (c+2)*32 relative to pointers advanced per macro-iter.
// ONE barrier per tile (top): makes tile t's staged data (all waves) visible.
// Write-after-read safety: stage of t+2 overwrites tile t-2's slot, whose
// reads completed before the tile-(t-1) barrier.
#define TILE(c)                                                               \
    {                                                                         \
        const int t_ = tb + (c);                                              \
        constexpr int SB_ = ((c) & 1) * 32768;          /* read slot, bytes */\
        constexpr int SS_ = (((c) + 2) & 3) * 16384;    /* stage slot, ush  */\
        constexpr int KO_ = ((c) + 2) * 32;             /* stage k, ushorts */\
        const char* const vA_ = vA[(c) >> 1];                                 \
        const char* const vB_ = vB[(c) >> 1];                                 \
        const bool doStage_ = (t_ + 2) < NT;                                  \
        BAR();                                                                \
        if (doStage_) {                                                       \
            async16(sA0 + SS_, pa0 + KO_);                                    \
            async16(sB0 + SS_, pb0 + KO_);                                    \
            async16(sA1 + SS_, pa1 + KO_);                                    \
            async16(sB1 + SS_, pb1 + KO_);                                    \
        }                                                                     \
        bf16x8 af[8], bf[4];                                                  \
        _Pragma("unroll")                                                     \
        for (int j = 0; j < 4; ++j)                                           \
            bf[j] = *(const bf16x8*)(vB_ + SB_ + j * 1024);                   \
        _Pragma("unroll")                                                     \
        for (int i = 0; i < 8; ++i)                                           \
            af[i] = *(const bf16x8*)(vA_ + SB_ + i * 1024);                   \
        __builtin_amdgcn_s_setprio(1);                                        \
        _Pragma("unroll")                                                     \
        for (int i = 0; i < 8; ++i)                                           \
            _Pragma("unroll")                                                 \
            for (int j = 0; j < 4; ++j)                                       \
                acc[i][j] = __builtin_amdgcn_mfma_f32_16x16x32_bf16(          \
                    af[i], bf[j], acc[i][j], 0, 0, 0);                        \
        __builtin_amdgcn_s_setprio(0);                                        \
        if (t_ < NT - 2)                                                      \
            asm volatile("s_waitcnt vmcnt(4)" ::: "memory");                  \
        else if (t_ == NT - 2)                                                \
            asm volatile("s_waitcnt vmcnt(0)" ::: "memory");                  \
    }

    for (int mt = 0; mt < NTM; ++mt) {
        const int tb = mt << 2;
        TILE(0)
        TILE(1)
        TILE(2)
        TILE(3)
        pa0 += 128; pa1 += 128; pb0 += 128; pb1 += 128;
    }
#undef TILE

    // ---- epilogue: C/D layout col=lane&15, row=(lane>>4)*4+reg ----
    const int er = (lane >> 4) * 4;
    const int ec = lane & 15;
#pragma unroll
    for (int j = 0; j < 4; ++j) {
        const int col = col0 + wn + j * 16 + ec;
        const float bz = bias[col];
#pragma unroll
        for (int i = 0; i < 8; ++i) {
            const size_t rbase = (size_t)(row0 + wm + i * 16 + er) * N + col;
#pragma unroll
            for (int r = 0; r < 4; ++r)
                __builtin_nontemporal_store(acc[i][j][r] + bz,
                                            &C[rbase + (size_t)r * N]);
        }
    }
}

extern "C" void kernel_launch(void* const* d_in, const int* in_sizes, int n_in,
                              void* d_out, int out_size, void* d_ws, size_t ws_size,
                              hipStream_t stream) {
    const float* x    = (const float*)d_in[0];   // [M][K]
    const float* w    = (const float*)d_in[1];   // [N][K]
    const float* c1   = (const float*)d_in[2];
    const float* c2   = (const float*)d_in[3];
    const float* bias = (const float*)d_in[4];   // [N]
    float* out = (float*)d_out;

    const int DOUT = in_sizes[4];                // 4096
    const int DIN  = in_sizes[1] / DOUT;         // 1024
    const int M    = in_sizes[0] / DIN;          // 16384
    const int N    = DOUT;
    const int K    = DIN;

    // workspace: x_bf16 (M*K ushort) then w_bf16 (N*K ushort) = 40 MB
    ushort* xb = (ushort*)d_ws;
    ushort* wb = xb + (size_t)M * K;

    const int nx4 = (M * K) / 4;
    const int nw4 = (N * K) / 4;
    prep_kernel<<<2048, 256, 0, stream>>>((const float4*)x, (ushort4*)xb, nx4,
                                          (const float4*)w, (ushort4*)wb, nw4,
                                          c1, c2);

    dim3 grid((M / 256) * (N / 256));            // 1024 blocks
    gemm_bin<<<grid, 512, 0, stream>>>(xb, wb, bias, out, M, N, K);
}